// Round 1
// baseline (546.409 us; speedup 1.0000x reference)
//
#include <hip/hip_runtime.h>

constexpr int B = 8, T = 128, T_KEEP = 64, C = 128, F = 32, K = 64;
constexpr int CF = C * F;                    // 4096
constexpr int TOTAL = B * T_KEEP * C * F;    // 2,097,152 kept elements
constexpr int BLOCK = 256;
constexpr int EPT = 4;                       // elements per thread
constexpr int EPB = BLOCK * EPT;             // 1024 elements per block

typedef float vfloat4 __attribute__((ext_vector_type(4)));

// Single fused kernel.
// Each block: (a) computes its (block-uniform) kept time index via stable-rank
// over masktime in LDS, (b) argmin-assigns 1024 elements (4/thread), (c) emits
// one-hot rows via wave-transposed, fully-coalesced float4 stores.
//
// Round-N changes vs previous best (544.5 us):
//  - Dropped __builtin_nontemporal_store: the harness fill sustains 6.3 TB/s
//    with plain stores; NT (no L2-allocate) is the suspected 2.4x write-BW
//    loss on the 537 MB output stream.
//  - Pack the 4 per-lane argmin indices (each <64) into ONE u32 and shuffle
//    16x up front (instead of 64 shfl interleaved with stores). The 64-store
//    loop is now a pure sequential store clause with zero LDS waits inside.
__global__ void __launch_bounds__(BLOCK) assign_onehot_fused(
        const float* __restrict__ y,
        const float* __restrict__ mask,
        const float* __restrict__ centers,
        float* __restrict__ out) {
    __shared__ float sc[K];
    __shared__ float m_s[T];
    __shared__ int keep_s;
    const int tid = threadIdx.x;

    if (tid < K) sc[tid] = centers[tid];
    if (tid < T) m_s[tid] = mask[(size_t)tid * CF];   // mask[0, t, 0, 0]
    __syncthreads();

    // stable ascending rank; this block covers kept-time index t_blk.
    // t changes every 4096 elems (EPB=1024 -> every 4 blocks) and repeats
    // per batch -> mask with T_KEEP-1.
    const int t_blk = (blockIdx.x >> 2) & (T_KEEP - 1);
    if (tid < T) {
        float mt = m_s[tid];
        int rank = 0;
        #pragma unroll 8
        for (int j = 0; j < T; ++j) {
            float mj = m_s[j];
            rank += (mj < mt) || (mj == mt && j < tid);
        }
        if (rank == t_blk) keep_s = tid;   // rank is a permutation -> unique
    }
    __syncthreads();
    const int keep_t = keep_s;

    const int lane = tid & 63;
    const int wave = tid >> 6;
    const int wbase = blockIdx.x * EPB + wave * (EPT * 64);  // wave's first kept elem

    // source addresses: kept index g = wbase + e*64 + lane, contiguous in (c,f)
    const int b   = wbase >> 18;             // / (T_KEEP*C*F)
    const int cf0 = wbase & (CF - 1);
    const float* ysrc = y + (size_t)b * (T * CF) + (size_t)keep_t * CF + cf0;

    const float x0 = ysrc[lane];
    const float x1 = ysrc[64 + lane];
    const float x2 = ysrc[128 + lane];
    const float x3 = ysrc[192 + lane];

    int bi0 = 0, bi1 = 0, bi2 = 0, bi3 = 0;
    float bd0 = __builtin_inff(), bd1 = bd0, bd2 = bd0, bd3 = bd0;
    const float4* c4 = (const float4*)sc;
    #pragma unroll
    for (int k4 = 0; k4 < K / 4; ++k4) {
        float4 cv = c4[k4];
        float d;
        #define UPD(cvx, kk)                                            \
            d = fabsf(x0 - cvx); if (d < bd0) { bd0 = d; bi0 = kk; }    \
            d = fabsf(x1 - cvx); if (d < bd1) { bd1 = d; bi1 = kk; }    \
            d = fabsf(x2 - cvx); if (d < bd2) { bd2 = d; bi2 = kk; }    \
            d = fabsf(x3 - cvx); if (d < bd3) { bd3 = d; bi3 = kk; }
        UPD(cv.x, 4 * k4 + 0)
        UPD(cv.y, 4 * k4 + 1)
        UPD(cv.z, 4 * k4 + 2)
        UPD(cv.w, 4 * k4 + 3)
        #undef UPD
    }

    // Pack the 4 argmin indices (each < 64) of this lane into one word.
    const int packed = bi0 | (bi1 << 8) | (bi2 << 16) | (bi3 << 24);

    // Hoisted transpose: store instr i4 covers rows i4*4+(lane>>4); that row's
    // argmin lives in byte (i4>>4) of lane (i4&15)*4+(lane>>4)'s packed word.
    // Since the source lane only depends on (i4 & 15), 16 shuffles fetch all
    // 64 per-store indices up front.
    const int sl_add = lane >> 4;
    int pk[16];
    #pragma unroll
    for (int s = 0; s < 16; ++s)
        pk[s] = __shfl(packed, s * 4 + sl_add, 64);

    // wave-transposed coalesced one-hot stores: wave region = 256 rows x 64
    // floats = 64 KB contiguous, written as a pure sequential store clause.
    vfloat4* out4 = (vfloat4*)out;
    const size_t obase = (size_t)wbase * (K / 4);
    const int k0 = (lane & 15) * 4;
    #pragma unroll
    for (int i4 = 0; i4 < 64; ++i4) {
        const int e = i4 >> 4;                       // compile-time per iter
        const int bsrc = (pk[i4 & 15] >> (8 * e)) & 0xff;
        vfloat4 v;
        v.x = (k0 + 0 == bsrc) ? 1.0f : 0.0f;
        v.y = (k0 + 1 == bsrc) ? 1.0f : 0.0f;
        v.z = (k0 + 2 == bsrc) ? 1.0f : 0.0f;
        v.w = (k0 + 3 == bsrc) ? 1.0f : 0.0f;
        out4[obase + i4 * 64 + lane] = v;
    }
}

extern "C" void kernel_launch(void* const* d_in, const int* in_sizes, int n_in,
                              void* d_out, int out_size, void* d_ws, size_t ws_size,
                              hipStream_t stream) {
    const float* y       = (const float*)d_in[0];
    const float* mask    = (const float*)d_in[1];
    const float* centers = (const float*)d_in[2];
    float* out = (float*)d_out;

    assign_onehot_fused<<<TOTAL / EPB, BLOCK, 0, stream>>>(y, mask, centers, out);
}

// Round 2
// 545.250 us; speedup vs baseline: 1.0021x; 1.0021x over previous
//
#include <hip/hip_runtime.h>

constexpr int B = 8, T = 128, T_KEEP = 64, C = 128, F = 32, K = 64;
constexpr int CF = C * F;                 // 4096 rows per (b,t) slice
constexpr int BLOCK = 256;
constexpr int CHUNK = 1024;               // rows per chunk (block-wide)
constexpr int NCHUNK = CF / CHUNK;        // 4 chunks per slice

typedef float vfloat4 __attribute__((ext_vector_type(4)));

// One block = one (b, kept-slot) output slice (4096 rows x 64 one-hot floats
// = 1 MiB). Structural changes vs the 546 us version:
//  - grid 512 (was 2048): mask-gather + rank + barriers run once per slice,
//    not once per quarter-slice.
//  - per-lane float4 y loads: lane owns 4 CONSECUTIVE rows -> the store-side
//    transpose becomes v_readlane (compile-time lane id), no LDS/bpermute.
//  - chunk software pipeline: chunk p+1's y load is issued before chunk p's
//    64-store clause, so its latency hides under the store drain.
__global__ void __launch_bounds__(BLOCK) assign_onehot_slice(
        const float* __restrict__ y,
        const float* __restrict__ mask,
        const float* __restrict__ centers,
        float* __restrict__ out) {
    __shared__ float sc[K];
    __shared__ float m_s[T];
    __shared__ int keep_s;
    const int tid = threadIdx.x;
    const int bid = blockIdx.x;
    const int b     = bid >> 6;              // / T_KEEP
    const int t_blk = bid & (T_KEEP - 1);    // kept slot this block emits

    if (tid < K) sc[tid] = centers[tid];
    if (tid < T) m_s[tid] = mask[(size_t)tid * CF];   // mask[0, t, 0, 0]
    __syncthreads();

    // stable ascending rank over masktime; unique writer since rank is a
    // permutation of 0..T-1.
    if (tid < T) {
        float mt = m_s[tid];
        int rank = 0;
        #pragma unroll 8
        for (int j = 0; j < T; ++j) {
            float mj = m_s[j];
            rank += (mj < mt) || (mj == mt && j < tid);
        }
        if (rank == t_blk) keep_s = tid;
    }
    __syncthreads();
    const int keep_t = keep_s;

    const int lane = tid & 63;
    const int wave = tid >> 6;

    // Lane owns rows {r0+4*lane+e, e=0..3} of chunk p, r0 = p*1024 + wave*256.
    // One float4 load per chunk covers all 4 rows (consecutive addresses).
    const float4* y4w = (const float4*)(y + (size_t)b * (T * CF)
                                          + (size_t)keep_t * CF)
                        + wave * 64 + lane;

    // Output slice base: out rows are (b*T_KEEP + t_blk)*CF + local_row = slot
    // ordering == bid ordering. Wave's chunk-p store region is 64 KiB
    // contiguous: out4 idx = (bid*4096 + p*1024 + wave*256)*16 + i4*64 + lane.
    vfloat4* ow = (vfloat4*)out
                + ((size_t)bid * CF + wave * 256) * (K / 4) + lane;

    const int hi = lane >> 4;          // which of the owner's 4 rows
    const int sh = hi * 8;             // byte select in packed word
    const int k0 = (lane & 15) * 4;    // this lane's 4 one-hot columns
    const float4* c4 = (const float4*)sc;

    float4 cur = y4w[0];
    for (int p = 0; p < NCHUNK; ++p) {
        // issue next chunk's load before this chunk's compute+store clause
        float4 nxt = (p + 1 < NCHUNK) ? y4w[(p + 1) * 256] : cur;

        // ---- argmin over 64 centers for the lane's 4 rows ----
        int bi0 = 0, bi1 = 0, bi2 = 0, bi3 = 0;
        float bd0 = __builtin_inff(), bd1 = bd0, bd2 = bd0, bd3 = bd0;
        #pragma unroll
        for (int k4 = 0; k4 < K / 4; ++k4) {
            float4 cv = c4[k4];
            float d;
            #define UPD(cvx, kk)                                            \
                d = fabsf(cur.x - cvx); if (d < bd0) { bd0 = d; bi0 = kk; } \
                d = fabsf(cur.y - cvx); if (d < bd1) { bd1 = d; bi1 = kk; } \
                d = fabsf(cur.z - cvx); if (d < bd2) { bd2 = d; bi2 = kk; } \
                d = fabsf(cur.w - cvx); if (d < bd3) { bd3 = d; bi3 = kk; }
            UPD(cv.x, 4 * k4 + 0)
            UPD(cv.y, 4 * k4 + 1)
            UPD(cv.z, 4 * k4 + 2)
            UPD(cv.w, 4 * k4 + 3)
            #undef UPD
        }
        const int packed = bi0 | (bi1 << 8) | (bi2 << 16) | (bi3 << 24);

        // ---- 64 coalesced float4 stores; row owner of store i4 is lane i4,
        //      element hi -> pure readlane broadcast, no LDS traffic ----
        vfloat4* op = ow + p * (CHUNK * (K / 4));
        #pragma unroll
        for (int i4 = 0; i4 < 64; ++i4) {
            const int pk   = __builtin_amdgcn_readlane(packed, i4);
            const int bsrc = (pk >> sh) & 0xff;
            vfloat4 v;
            v.x = (bsrc == k0 + 0) ? 1.0f : 0.0f;
            v.y = (bsrc == k0 + 1) ? 1.0f : 0.0f;
            v.z = (bsrc == k0 + 2) ? 1.0f : 0.0f;
            v.w = (bsrc == k0 + 3) ? 1.0f : 0.0f;
            op[i4 * 64] = v;
        }
        cur = nxt;
    }
}

extern "C" void kernel_launch(void* const* d_in, const int* in_sizes, int n_in,
                              void* d_out, int out_size, void* d_ws, size_t ws_size,
                              hipStream_t stream) {
    const float* y       = (const float*)d_in[0];
    const float* mask    = (const float*)d_in[1];
    const float* centers = (const float*)d_in[2];
    float* out = (float*)d_out;

    assign_onehot_slice<<<B * T_KEEP, BLOCK, 0, stream>>>(y, mask, centers, out);
}